// Round 1
// baseline (14918.301 us; speedup 1.0000x reference)
//
#include <hip/hip_runtime.h>
#include <math.h>

#define NB 128
#define NP 196
#define NENC 2048
#define NE 512
#define ND 512
#define NA 512
#define NV 10000
#define NL 52
#define NT 51

#define BK 16
#define BM 128
#define BN 64

__device__ __forceinline__ float sigmoidf(float v) { return 1.0f / (1.0f + __expf(-v)); }

// ---------------- sort (stable, descending by length) ----------------
__global__ void kSort(const int* __restrict__ cap_len, const int* __restrict__ captions,
                      int* __restrict__ order, int* __restrict__ dlen,
                      float* __restrict__ out_cap, float* __restrict__ out_dlen) {
  __shared__ int lens[NB];
  int tid = threadIdx.x;
  lens[tid] = cap_len[tid];
  __syncthreads();
  int li = lens[tid];
  int r = 0;
  for (int j = 0; j < NB; ++j) {
    int lj = lens[j];
    if (lj > li || (lj == li && j < tid)) r++;
  }
  order[r] = tid;
  dlen[r] = li - 1;
  out_dlen[r] = (float)(li - 1);
  for (int l = 0; l < NL; ++l)
    out_cap[(size_t)r * NL + l] = (float)captions[(size_t)tid * NL + l];
}

// ---------------- zero helper ----------------
__global__ void kZero(float* __restrict__ ptr, int n) {
  int i = blockIdx.x * 256 + threadIdx.x;
  if (i < n) ptr[i] = 0.0f;
}

// ---------------- eo = mean over P ----------------
__global__ void kEo(const float* __restrict__ features, const int* __restrict__ order,
                    float* __restrict__ eo) {
  int e = blockIdx.x * 256 + threadIdx.x;
  int b = blockIdx.y;
  const float* f = features + (size_t)order[b] * NP * NENC + e;
  float s = 0.0f;
  for (int p = 0; p < NP; ++p) s += f[(size_t)p * NENC];
  eo[(size_t)b * NENC + e] = s * (1.0f / NP);
}

// ---------------- h0 / c0 ----------------
__global__ void kInitHC(const float* __restrict__ eo,
                        const float* __restrict__ W_h0, const float* __restrict__ b_h0,
                        const float* __restrict__ W_c0, const float* __restrict__ b_c0,
                        float* __restrict__ h, float* __restrict__ c) {
  __shared__ float s_eo[NENC];
  int b = blockIdx.y;
  for (int i = threadIdx.x; i < NENC; i += 256) s_eo[i] = eo[(size_t)b * NENC + i];
  __syncthreads();
  int d = blockIdx.x * 256 + threadIdx.x;
  const float* W = blockIdx.z ? W_c0 : W_h0;
  const float* bias = blockIdx.z ? b_c0 : b_h0;
  float* out = blockIdx.z ? c : h;
  float acc = bias[d];
  for (int k = 0; k < NENC; ++k) acc += s_eo[k] * W[(size_t)k * ND + d];
  out[(size_t)b * ND + d] = acc;
}

// ---------------- enc_proj = features_sorted @ W_enc_att + b ----------------
__global__ __launch_bounds__(256) void kEncProj(const float* __restrict__ features,
                                                const int* __restrict__ order,
                                                const float* __restrict__ W,
                                                const float* __restrict__ bias,
                                                float* __restrict__ out) {
  __shared__ float As[BK][BM + 1];
  __shared__ float Ws[BK][BN];
  int tid = threadIdx.x;
  int nb = blockIdx.x * BN;
  int mb = blockIdx.y * BM;
  int tm = (tid >> 4) * 8;
  int tn = (tid & 15) * 4;
  size_t rowoff[8];
  int mloc[8], kloc[8];
#pragma unroll
  for (int i = 0; i < 8; ++i) {
    int idx = i * 256 + tid;
    int m = idx >> 4;
    int kk = idx & 15;
    mloc[i] = m; kloc[i] = kk;
    int gm = mb + m;
    int b = gm / NP;
    int pp = gm - b * NP;
    rowoff[i] = ((size_t)order[b] * NP + pp) * NENC + kk;
  }
  float acc[8][4] = {};
  for (int k0 = 0; k0 < NENC; k0 += BK) {
#pragma unroll
    for (int i = 0; i < 8; ++i) As[kloc[i]][mloc[i]] = features[rowoff[i] + k0];
#pragma unroll
    for (int i = 0; i < 4; ++i) {
      int idx = i * 256 + tid;
      int kk = idx >> 6;
      int n = idx & 63;
      Ws[kk][n] = W[(size_t)(k0 + kk) * NA + nb + n];
    }
    __syncthreads();
#pragma unroll
    for (int kk = 0; kk < BK; ++kk) {
      float a[8], wv[4];
#pragma unroll
      for (int i = 0; i < 8; ++i) a[i] = As[kk][tm + i];
#pragma unroll
      for (int j = 0; j < 4; ++j) wv[j] = Ws[kk][tn + j];
#pragma unroll
      for (int i = 0; i < 8; ++i)
#pragma unroll
        for (int j = 0; j < 4; ++j) acc[i][j] += a[i] * wv[j];
    }
    __syncthreads();
  }
#pragma unroll
  for (int i = 0; i < 8; ++i)
#pragma unroll
    for (int j = 0; j < 4; ++j)
      out[(size_t)(mb + tm + i) * NA + nb + tn + j] = acc[i][j] + bias[nb + tn + j];
}

// ---------------- dec_proj & beta-gate (pre-sigmoid), split-K atomic ----------------
__global__ __launch_bounds__(256) void kDecGate(const float* __restrict__ h,
                                                const float* __restrict__ W_dec, const float* __restrict__ b_dec,
                                                const float* __restrict__ W_beta, const float* __restrict__ b_beta,
                                                float* __restrict__ dec_proj, float* __restrict__ gate_raw) {
  __shared__ float As[BK][BM + 1];
  __shared__ float Ws[BK][BN];
  int tid = threadIdx.x;
  bool isDec = blockIdx.x < (NA / BN);
  const float* W; const float* bias; float* out; int N; int nb;
  if (isDec) { W = W_dec; bias = b_dec; out = dec_proj; N = NA; nb = blockIdx.x * BN; }
  else { W = W_beta; bias = b_beta; out = gate_raw; N = NENC; nb = ((int)blockIdx.x - NA / BN) * BN; }
  int k_lo = blockIdx.y * (ND / 2);
  int tm = (tid >> 4) * 8, tn = (tid & 15) * 4;
  float acc[8][4] = {};
  for (int k0 = k_lo; k0 < k_lo + ND / 2; k0 += BK) {
#pragma unroll
    for (int i = 0; i < 8; ++i) {
      int idx = i * 256 + tid; int m = idx >> 4; int kk = idx & 15;
      As[kk][m] = h[(size_t)m * ND + k0 + kk];
    }
#pragma unroll
    for (int i = 0; i < 4; ++i) {
      int idx = i * 256 + tid; int kk = idx >> 6; int n = idx & 63;
      Ws[kk][n] = W[(size_t)(k0 + kk) * N + nb + n];
    }
    __syncthreads();
#pragma unroll
    for (int kk = 0; kk < BK; ++kk) {
      float a[8], wv[4];
#pragma unroll
      for (int i = 0; i < 8; ++i) a[i] = As[kk][tm + i];
#pragma unroll
      for (int j = 0; j < 4; ++j) wv[j] = Ws[kk][tn + j];
#pragma unroll
      for (int i = 0; i < 8; ++i)
#pragma unroll
        for (int j = 0; j < 4; ++j) acc[i][j] += a[i] * wv[j];
    }
    __syncthreads();
  }
#pragma unroll
  for (int i = 0; i < 8; ++i)
#pragma unroll
    for (int j = 0; j < 4; ++j) {
      float v = acc[i][j];
      if (blockIdx.y == 0) v += bias[nb + tn + j];
      atomicAdd(&out[(size_t)(tm + i) * N + nb + tn + j], v);
    }
}

// ---------------- scores + softmax -> alpha ----------------
__global__ __launch_bounds__(256) void kScores(const float* __restrict__ enc_proj,
                                               const float* __restrict__ dec_proj,
                                               const float* __restrict__ w_full,
                                               const float* __restrict__ b_full,
                                               const int* __restrict__ dlen, int t,
                                               float* __restrict__ alpha,
                                               float* __restrict__ out_alph) {
  int b = blockIdx.x;
  __shared__ float s_dp[NA];
  __shared__ float s_wf[NA];
  __shared__ float s_sc[NP];
  __shared__ float red[8];
  int tid = threadIdx.x;
  for (int i = tid; i < NA; i += 256) { s_dp[i] = dec_proj[(size_t)b * NA + i]; s_wf[i] = w_full[i]; }
  __syncthreads();
  int wave = tid >> 6, lane = tid & 63;
  float bf = b_full[0];
  const float* ep = enc_proj + (size_t)b * NP * NA;
  for (int p = wave; p < NP; p += 4) {
    float acc = 0.0f;
    for (int a = lane; a < NA; a += 64) {
      float v = ep[(size_t)p * NA + a] + s_dp[a];
      acc += fmaxf(v, 0.0f) * s_wf[a];
    }
#pragma unroll
    for (int off = 32; off; off >>= 1) acc += __shfl_down(acc, off);
    if (lane == 0) s_sc[p] = acc + bf;
  }
  __syncthreads();
  float mx = -3.4e38f;
  for (int p = tid; p < NP; p += 256) mx = fmaxf(mx, s_sc[p]);
#pragma unroll
  for (int off = 32; off; off >>= 1) mx = fmaxf(mx, __shfl_down(mx, off));
  if (lane == 0) red[wave] = mx;
  __syncthreads();
  if (tid == 0) red[0] = fmaxf(fmaxf(red[0], red[1]), fmaxf(red[2], red[3]));
  __syncthreads();
  float m2 = red[0];
  float sm = 0.0f;
  for (int p = tid; p < NP; p += 256) { float e = __expf(s_sc[p] - m2); s_sc[p] = e; sm += e; }
#pragma unroll
  for (int off = 32; off; off >>= 1) sm += __shfl_down(sm, off);
  if (lane == 0) red[4 + wave] = sm;
  __syncthreads();
  if (tid == 0) red[4] = 1.0f / (red[4] + red[5] + red[6] + red[7]);
  __syncthreads();
  float inv = red[4];
  float mk = (dlen[b] > t) ? 1.0f : 0.0f;
  for (int p = tid; p < NP; p += 256) {
    float al = s_sc[p] * inv;
    alpha[(size_t)b * NP + p] = al;
    out_alph[((size_t)b * NT + t) * NP + p] = al * mk;
  }
}

// ---------------- x = [e_t | sigmoid(gate_raw) * (alpha @ features)] ----------------
__global__ __launch_bounds__(256) void kAttwX(const float* __restrict__ features,
                                              const int* __restrict__ order,
                                              const int* __restrict__ captions,
                                              const float* __restrict__ emb,
                                              const float* __restrict__ alpha,
                                              const float* __restrict__ gate_raw,
                                              int t, float* __restrict__ x) {
  int b = blockIdx.y;
  int chunk = blockIdx.x;
  int tid = threadIdx.x;
  if (chunk < 2) {
    int j = chunk * 256 + tid;
    int tok = captions[(size_t)order[b] * NL + t];
    x[(size_t)b * (NE + NENC) + j] = emb[(size_t)tok * NE + j];
  } else {
    __shared__ float s_al[NP];
    for (int i = tid; i < NP; i += 256) s_al[i] = alpha[(size_t)b * NP + i];
    __syncthreads();
    int e = (chunk - 2) * 256 + tid;
    const float* f = features + (size_t)order[b] * NP * NENC + e;
    float acc = 0.0f;
    for (int p = 0; p < NP; ++p) acc += s_al[p] * f[(size_t)p * NENC];
    float g = sigmoidf(gate_raw[(size_t)b * NENC + e]);
    x[(size_t)b * (NE + NENC) + NE + e] = acc * g;
  }
}

// ---------------- gates = x @ W_ih + h @ W_hh + b_ih + b_hh (split-K atomic) ----------------
__global__ __launch_bounds__(256) void kGates(const float* __restrict__ x, const float* __restrict__ h,
                                              const float* __restrict__ W_ih, const float* __restrict__ b_ih,
                                              const float* __restrict__ W_hh, const float* __restrict__ b_hh,
                                              float* __restrict__ gates) {
  __shared__ float As[BK][BM + 1];
  __shared__ float Ws[BK][BN];
  int tid = threadIdx.x;
  int nb = blockIdx.x * BN;
  bool isH = (blockIdx.y == 5);
  const float* Asrc = isH ? h : x;
  int astride = isH ? ND : (NE + NENC);
  const float* W = isH ? W_hh : W_ih;
  int k_lo = isH ? 0 : blockIdx.y * 512;
  int tm = (tid >> 4) * 8, tn = (tid & 15) * 4;
  float acc[8][4] = {};
  for (int k0 = k_lo; k0 < k_lo + 512; k0 += BK) {
#pragma unroll
    for (int i = 0; i < 8; ++i) {
      int idx = i * 256 + tid; int m = idx >> 4; int kk = idx & 15;
      As[kk][m] = Asrc[(size_t)m * astride + k0 + kk];
    }
#pragma unroll
    for (int i = 0; i < 4; ++i) {
      int idx = i * 256 + tid; int kk = idx >> 6; int n = idx & 63;
      Ws[kk][n] = W[(size_t)(k0 + kk) * NENC + nb + n];
    }
    __syncthreads();
#pragma unroll
    for (int kk = 0; kk < BK; ++kk) {
      float a[8], wv[4];
#pragma unroll
      for (int i = 0; i < 8; ++i) a[i] = As[kk][tm + i];
#pragma unroll
      for (int j = 0; j < 4; ++j) wv[j] = Ws[kk][tn + j];
#pragma unroll
      for (int i = 0; i < 8; ++i)
#pragma unroll
        for (int j = 0; j < 4; ++j) acc[i][j] += a[i] * wv[j];
    }
    __syncthreads();
  }
#pragma unroll
  for (int i = 0; i < 8; ++i)
#pragma unroll
    for (int j = 0; j < 4; ++j) {
      float v = acc[i][j];
      if (isH) v += b_ih[nb + tn + j] + b_hh[nb + tn + j];
      atomicAdd(&gates[(size_t)(tm + i) * NENC + nb + tn + j], v);
    }
}

// ---------------- LSTM cell elementwise ----------------
__global__ void kLstm(const float* __restrict__ gates, const int* __restrict__ dlen, int t,
                      float* __restrict__ h, float* __restrict__ c, float* __restrict__ hnew) {
  int idx = blockIdx.x * 256 + threadIdx.x;   // 0 .. NB*ND-1
  int b = idx >> 9;
  int d = idx & 511;
  const float* g = gates + (size_t)b * NENC;
  float gi = g[d];
  float gf = g[512 + d];
  float gg = g[1024 + d];
  float go = g[1536 + d];
  float cn = sigmoidf(gf) * c[idx] + sigmoidf(gi) * tanhf(gg);
  float hn = sigmoidf(go) * tanhf(cn);
  hnew[idx] = hn;
  if (dlen[b] > t) { h[idx] = hn; c[idx] = cn; }
}

// ---------------- preds = hnew @ W_fc + b_fc (masked write to out) ----------------
__global__ __launch_bounds__(256) void kPreds(const float* __restrict__ hnew,
                                              const float* __restrict__ W_fc,
                                              const float* __restrict__ b_fc,
                                              const int* __restrict__ dlen, int t,
                                              float* __restrict__ out_pred) {
  __shared__ float As[BK][BM + 1];
  __shared__ float Ws[BK][BN];
  int tid = threadIdx.x;
  int nb = blockIdx.x * BN;
  int tm = (tid >> 4) * 8, tn = (tid & 15) * 4;
  float acc[8][4] = {};
  for (int k0 = 0; k0 < ND; k0 += BK) {
#pragma unroll
    for (int i = 0; i < 8; ++i) {
      int idx = i * 256 + tid; int m = idx >> 4; int kk = idx & 15;
      As[kk][m] = hnew[(size_t)m * ND + k0 + kk];
    }
#pragma unroll
    for (int i = 0; i < 4; ++i) {
      int idx = i * 256 + tid; int kk = idx >> 6; int n = idx & 63;
      int gn = nb + n;
      Ws[kk][n] = (gn < NV) ? W_fc[(size_t)(k0 + kk) * NV + gn] : 0.0f;
    }
    __syncthreads();
#pragma unroll
    for (int kk = 0; kk < BK; ++kk) {
      float a[8], wv[4];
#pragma unroll
      for (int i = 0; i < 8; ++i) a[i] = As[kk][tm + i];
#pragma unroll
      for (int j = 0; j < 4; ++j) wv[j] = Ws[kk][tn + j];
#pragma unroll
      for (int i = 0; i < 8; ++i)
#pragma unroll
        for (int j = 0; j < 4; ++j) acc[i][j] += a[i] * wv[j];
    }
    __syncthreads();
  }
#pragma unroll
  for (int i = 0; i < 8; ++i)
#pragma unroll
    for (int j = 0; j < 4; ++j) {
      int gn = nb + tn + j;
      if (gn < NV) {
        int m = tm + i;
        float mk = (dlen[m] > t) ? 1.0f : 0.0f;
        out_pred[((size_t)m * NT + t) * NV + gn] = mk * (acc[i][j] + b_fc[gn]);
      }
    }
}

extern "C" void kernel_launch(void* const* d_in, const int* in_sizes, int n_in,
                              void* d_out, int out_size, void* d_ws, size_t ws_size,
                              hipStream_t stream) {
  (void)in_sizes; (void)n_in; (void)out_size; (void)ws_size;
  const float* features  = (const float*)d_in[0];
  const int*   captions  = (const int*)d_in[1];
  const int*   cap_len   = (const int*)d_in[2];
  const float* emb       = (const float*)d_in[3];
  const float* W_enc_att = (const float*)d_in[4];
  const float* b_enc_att = (const float*)d_in[5];
  const float* W_dec_att = (const float*)d_in[6];
  const float* b_dec_att = (const float*)d_in[7];
  const float* w_full    = (const float*)d_in[8];
  const float* b_full    = (const float*)d_in[9];
  const float* W_h0      = (const float*)d_in[10];
  const float* b_h0      = (const float*)d_in[11];
  const float* W_c0      = (const float*)d_in[12];
  const float* b_c0      = (const float*)d_in[13];
  const float* W_beta    = (const float*)d_in[14];
  const float* b_beta    = (const float*)d_in[15];
  const float* W_ih      = (const float*)d_in[16];
  const float* b_ih      = (const float*)d_in[17];
  const float* W_hh      = (const float*)d_in[18];
  const float* b_hh      = (const float*)d_in[19];
  const float* W_fc      = (const float*)d_in[20];
  const float* b_fc      = (const float*)d_in[21];

  float* out      = (float*)d_out;
  float* out_pred = out;
  float* out_cap  = out_pred + (size_t)NB * NT * NV;
  float* out_dlen = out_cap + (size_t)NB * NL;
  float* out_alph = out_dlen + NB;

  char* p = (char*)d_ws;
  auto alloc = [&](size_t nbytes) { void* r = (void*)p; p += (nbytes + 255) & ~(size_t)255; return r; };
  int*   order    = (int*)alloc(NB * 4);
  int*   dlen     = (int*)alloc(NB * 4);
  float* eo       = (float*)alloc((size_t)NB * NENC * 4);
  float* h        = (float*)alloc((size_t)NB * ND * 4);
  float* c        = (float*)alloc((size_t)NB * ND * 4);
  float* hnew     = (float*)alloc((size_t)NB * ND * 4);
  float* enc_proj = (float*)alloc((size_t)NB * NP * NA * 4);
  float* alpha    = (float*)alloc((size_t)NB * NP * 4);
  float* x        = (float*)alloc((size_t)NB * (NE + NENC) * 4);
  // contiguous zero region: dec_proj | gate_raw | gates
  int zcount = NB * NA + NB * NENC + NB * NENC;
  float* zregion  = (float*)alloc((size_t)zcount * 4);
  float* dec_proj = zregion;
  float* gate_raw = dec_proj + (size_t)NB * NA;
  float* gates    = gate_raw + (size_t)NB * NENC;

  kSort<<<1, NB, 0, stream>>>(cap_len, captions, order, dlen, out_cap, out_dlen);
  kEo<<<dim3(NENC / 256, NB), 256, 0, stream>>>(features, order, eo);
  kInitHC<<<dim3(ND / 256, NB, 2), 256, 0, stream>>>(eo, W_h0, b_h0, W_c0, b_c0, h, c);
  kEncProj<<<dim3(NA / BN, (NB * NP) / BM), 256, 0, stream>>>(features, order, W_enc_att, b_enc_att, enc_proj);

  for (int t = 0; t < NT; ++t) {
    kZero<<<(zcount + 255) / 256, 256, 0, stream>>>(zregion, zcount);
    kDecGate<<<dim3(NA / BN + NENC / BN, 2), 256, 0, stream>>>(h, W_dec_att, b_dec_att, W_beta, b_beta,
                                                               dec_proj, gate_raw);
    kScores<<<NB, 256, 0, stream>>>(enc_proj, dec_proj, w_full, b_full, dlen, t, alpha, out_alph);
    kAttwX<<<dim3(2 + NENC / 256, NB), 256, 0, stream>>>(features, order, captions, emb, alpha, gate_raw, t, x);
    kGates<<<dim3(NENC / BN, 6), 256, 0, stream>>>(x, h, W_ih, b_ih, W_hh, b_hh, gates);
    kLstm<<<(NB * ND) / 256, 256, 0, stream>>>(gates, dlen, t, h, c, hnew);
    kPreds<<<(NV + BN - 1) / BN, 256, 0, stream>>>(hnew, W_fc, b_fc, dlen, t, out_pred);
  }
}

// Round 2
// 8560.546 us; speedup vs baseline: 1.7427x; 1.7427x over previous
//
#include <hip/hip_runtime.h>
#include <math.h>

#define NB 128
#define NP 196
#define NENC 2048
#define NE 512
#define ND 512
#define NA 512
#define NV 10000
#define NVPAD 10112
#define NL 52
#define NT 51
#define KXH 3072   // [emb 512 | attw 2048 | h 512]

typedef unsigned short u16;
typedef __attribute__((ext_vector_type(8))) short bf16x8;
typedef __attribute__((ext_vector_type(8))) unsigned short u16x8;
typedef __attribute__((ext_vector_type(4))) float f32x4;

#define MFMA16 __builtin_amdgcn_mfma_f32_16x16x32_bf16

__device__ __forceinline__ float sigmoidf_(float v) { return 1.0f / (1.0f + __expf(-v)); }
__device__ __forceinline__ float b2f(u16 u) { return __uint_as_float(((unsigned int)u) << 16); }
__device__ __forceinline__ u16 f2b(float f) {
  unsigned int u = __float_as_uint(f);
  unsigned int r = (u + 0x7FFFu + ((u >> 16) & 1u)) >> 16;
  return (u16)r;
}

// ---------------- sort (stable, descending by length) ----------------
__global__ void kSort(const int* __restrict__ cap_len, const int* __restrict__ captions,
                      int* __restrict__ order, int* __restrict__ dlen,
                      float* __restrict__ out_cap, float* __restrict__ out_dlen) {
  __shared__ int lens[NB];
  int tid = threadIdx.x;
  lens[tid] = cap_len[tid];
  __syncthreads();
  int li = lens[tid];
  int r = 0;
  for (int j = 0; j < NB; ++j) {
    int lj = lens[j];
    if (lj > li || (lj == li && j < tid)) r++;
  }
  order[r] = tid;
  dlen[r] = li - 1;
  out_dlen[r] = (float)(li - 1);
  for (int l = 0; l < NL; ++l)
    out_cap[(size_t)r * NL + l] = (float)captions[(size_t)tid * NL + l];
}

// ---------------- features: gather sorted + f32 -> bf16 ----------------
__global__ void kFeats(const float* __restrict__ features, const int* __restrict__ order,
                       u16* __restrict__ featsb) {
  int p = blockIdx.x, b = blockIdx.y, tid = threadIdx.x;
  const float* src = features + ((size_t)order[b] * NP + p) * NENC + tid * 8;
  u16* dst = featsb + ((size_t)b * NP + p) * NENC + tid * 8;
  float4 v0 = *(const float4*)src;
  float4 v1 = *(const float4*)(src + 4);
  u16x8 o;
  o[0] = f2b(v0.x); o[1] = f2b(v0.y); o[2] = f2b(v0.z); o[3] = f2b(v0.w);
  o[4] = f2b(v1.x); o[5] = f2b(v1.y); o[6] = f2b(v1.z); o[7] = f2b(v1.w);
  *(u16x8*)dst = o;
}

// ---------------- weight transposes (one-time) ----------------
__global__ void kTWenc(const float* __restrict__ W, u16* __restrict__ dst) {
  int n = blockIdx.x;  // 512
  for (int k = threadIdx.x; k < NENC; k += 256)
    dst[(size_t)n * NENC + k] = f2b(W[(size_t)k * NA + n]);
}
__global__ void kTdg(const float* __restrict__ Wdec, const float* __restrict__ Wbeta,
                     u16* __restrict__ dst) {
  int n = blockIdx.x;  // 2560
  for (int k = threadIdx.x; k < ND; k += 256) {
    float v = (n < NA) ? Wdec[(size_t)k * NA + n] : Wbeta[(size_t)k * NENC + (n - NA)];
    dst[(size_t)n * ND + k] = f2b(v);
  }
}
__global__ void kTifgo(const float* __restrict__ Wih, const float* __restrict__ Whh,
                       u16* __restrict__ dst) {
  int n = blockIdx.x;  // 2048 (interleaved: d = n>>2, gate = n&3)
  int col = (n & 3) * ND + (n >> 2);
  for (int k = threadIdx.x; k < KXH; k += 256) {
    float v = (k < NE + NENC) ? Wih[(size_t)k * (4 * ND) + col]
                              : Whh[(size_t)(k - NE - NENC) * (4 * ND) + col];
    dst[(size_t)n * KXH + k] = f2b(v);
  }
}
__global__ void kTfc(const float* __restrict__ Wfc, u16* __restrict__ dst) {
  int n = blockIdx.x;  // NVPAD
  for (int k = threadIdx.x; k < ND; k += 256) {
    float v = (n < NV) ? Wfc[(size_t)k * NV + n] : 0.0f;
    dst[(size_t)n * ND + k] = f2b(v);
  }
}

// ---------------- eo = mean over P (from bf16 feats) ----------------
__global__ void kEo(const u16* __restrict__ featsb, float* __restrict__ eo) {
  int e = blockIdx.x * 256 + threadIdx.x;
  int b = blockIdx.y;
  const u16* f = featsb + (size_t)b * NP * NENC + e;
  float s = 0.0f;
  for (int p = 0; p < NP; ++p) s += b2f(f[(size_t)p * NENC]);
  eo[(size_t)b * NENC + e] = s * (1.0f / NP);
}

// ---------------- h0 / c0 ----------------
__global__ void kInitHC(const float* __restrict__ eo,
                        const float* __restrict__ W_h0, const float* __restrict__ b_h0,
                        const float* __restrict__ W_c0, const float* __restrict__ b_c0,
                        u16* __restrict__ hb, u16* __restrict__ xh, float* __restrict__ c) {
  __shared__ float s_eo[NENC];
  int b = blockIdx.y;
  for (int i = threadIdx.x; i < NENC; i += 256) s_eo[i] = eo[(size_t)b * NENC + i];
  __syncthreads();
  int d = blockIdx.x * 256 + threadIdx.x;
  const float* W = blockIdx.z ? W_c0 : W_h0;
  const float* bias = blockIdx.z ? b_c0 : b_h0;
  float acc = bias[d];
  for (int k = 0; k < NENC; ++k) acc += s_eo[k] * W[(size_t)k * ND + d];
  if (blockIdx.z) {
    c[(size_t)b * ND + d] = acc;
  } else {
    u16 hv = f2b(acc);
    hb[(size_t)b * ND + d] = hv;
    xh[(size_t)b * KXH + NE + NENC + d] = hv;
  }
}

// ---------------- enc_proj = featsb @ W_enc + b (MFMA, bf16 out) ----------------
__global__ __launch_bounds__(256) void kEncProj(const u16* __restrict__ A,   // [25088][2048]
                                                const u16* __restrict__ BT,  // [512][2048]
                                                const float* __restrict__ bias,
                                                u16* __restrict__ D) {       // [25088][512]
  int w = threadIdx.x >> 6, lane = threadIdx.x & 63;
  int lr = lane & 15, lg = lane >> 4;
  int mb = blockIdx.y * 128 + w * 32;
  int nb = blockIdx.x * 64;
  f32x4 acc[2][4] = {};
  const u16* a0 = A + (size_t)(mb + lr) * NENC + lg * 8;
  const u16* a1 = a0 + 16 * NENC;
  const u16* b0 = BT + (size_t)(nb + lr) * NENC + lg * 8;
  for (int k0 = 0; k0 < NENC; k0 += 32) {
    bf16x8 af0 = *(const bf16x8*)(a0 + k0);
    bf16x8 af1 = *(const bf16x8*)(a1 + k0);
#pragma unroll
    for (int nt = 0; nt < 4; ++nt) {
      bf16x8 bf = *(const bf16x8*)(b0 + (size_t)nt * 16 * NENC + k0);
      acc[0][nt] = MFMA16(af0, bf, acc[0][nt], 0, 0, 0);
      acc[1][nt] = MFMA16(af1, bf, acc[1][nt], 0, 0, 0);
    }
  }
#pragma unroll
  for (int mt = 0; mt < 2; ++mt)
#pragma unroll
    for (int nt = 0; nt < 4; ++nt)
#pragma unroll
      for (int j = 0; j < 4; ++j) {
        int row = mb + mt * 16 + lg * 4 + j;
        int col = nb + nt * 16 + lr;
        D[(size_t)row * NA + col] = f2b(acc[mt][nt][j] + bias[col]);
      }
}

// ---------------- dec_proj & gate_raw (MFMA) ----------------
__global__ __launch_bounds__(256) void kDecGate(const u16* __restrict__ hb,   // [128][512]
                                                const u16* __restrict__ BT,   // [2560][512]
                                                const float* __restrict__ b_dec,
                                                const float* __restrict__ b_beta,
                                                float* __restrict__ dec_proj,
                                                float* __restrict__ gate_raw) {
  int w = threadIdx.x >> 6, lane = threadIdx.x & 63;
  int lr = lane & 15, lg = lane >> 4;
  int mb = w * 32;
  int nb = blockIdx.x * 64;
  f32x4 acc[2][4] = {};
  const u16* a0 = hb + (size_t)(mb + lr) * ND + lg * 8;
  const u16* a1 = a0 + 16 * ND;
  const u16* b0 = BT + (size_t)(nb + lr) * ND + lg * 8;
  for (int k0 = 0; k0 < ND; k0 += 32) {
    bf16x8 af0 = *(const bf16x8*)(a0 + k0);
    bf16x8 af1 = *(const bf16x8*)(a1 + k0);
#pragma unroll
    for (int nt = 0; nt < 4; ++nt) {
      bf16x8 bf = *(const bf16x8*)(b0 + (size_t)nt * 16 * ND + k0);
      acc[0][nt] = MFMA16(af0, bf, acc[0][nt], 0, 0, 0);
      acc[1][nt] = MFMA16(af1, bf, acc[1][nt], 0, 0, 0);
    }
  }
#pragma unroll
  for (int mt = 0; mt < 2; ++mt)
#pragma unroll
    for (int nt = 0; nt < 4; ++nt)
#pragma unroll
      for (int j = 0; j < 4; ++j) {
        int row = mb + mt * 16 + lg * 4 + j;
        int n = nb + nt * 16 + lr;
        if (n < NA)
          dec_proj[(size_t)row * NA + n] = acc[mt][nt][j] + b_dec[n];
        else
          gate_raw[(size_t)row * NENC + (n - NA)] = acc[mt][nt][j] + b_beta[n - NA];
      }
}

// ---------------- scores + softmax + attw + x build (one block per b) ----------------
__global__ __launch_bounds__(256) void kSAX(const u16* __restrict__ featsb,
                                            const u16* __restrict__ enc_projb,
                                            const float* __restrict__ dec_proj,
                                            const float* __restrict__ gate_raw,
                                            const float* __restrict__ w_full,
                                            const float* __restrict__ b_full,
                                            const float* __restrict__ emb,
                                            const int* __restrict__ captions,
                                            const int* __restrict__ order,
                                            const int* __restrict__ dlen, int t,
                                            u16* __restrict__ xh,
                                            float* __restrict__ out_alph) {
  int b = blockIdx.x, tid = threadIdx.x;
  __shared__ float s_dp[NA], s_wf[NA], s_sc[NP], s_al[NP], red[8];
  for (int i = tid; i < NA; i += 256) { s_dp[i] = dec_proj[(size_t)b * NA + i]; s_wf[i] = w_full[i]; }
  __syncthreads();
  int wave = tid >> 6, lane = tid & 63;
  float bf_ = b_full[0];
  for (int p = wave; p < NP; p += 4) {
    const u16* ep = enc_projb + ((size_t)b * NP + p) * NA + lane * 8;
    u16x8 v = *(const u16x8*)ep;
    float acc = 0.0f;
#pragma unroll
    for (int j = 0; j < 8; ++j) {
      int a = lane * 8 + j;
      float vv = b2f(v[j]) + s_dp[a];
      acc += fmaxf(vv, 0.0f) * s_wf[a];
    }
#pragma unroll
    for (int off = 32; off; off >>= 1) acc += __shfl_down(acc, off);
    if (lane == 0) s_sc[p] = acc + bf_;
  }
  __syncthreads();
  float mx = -3.4e38f;
  for (int p = tid; p < NP; p += 256) mx = fmaxf(mx, s_sc[p]);
#pragma unroll
  for (int off = 32; off; off >>= 1) mx = fmaxf(mx, __shfl_down(mx, off));
  if (lane == 0) red[wave] = mx;
  __syncthreads();
  if (tid == 0) red[0] = fmaxf(fmaxf(red[0], red[1]), fmaxf(red[2], red[3]));
  __syncthreads();
  float m2 = red[0];
  float sm = 0.0f;
  for (int p = tid; p < NP; p += 256) { float e = __expf(s_sc[p] - m2); s_al[p] = e; sm += e; }
#pragma unroll
  for (int off = 32; off; off >>= 1) sm += __shfl_down(sm, off);
  if (lane == 0) red[4 + wave] = sm;
  __syncthreads();
  if (tid == 0) red[4] = 1.0f / (red[4] + red[5] + red[6] + red[7]);
  __syncthreads();
  float inv = red[4];
  float mk = (dlen[b] > t) ? 1.0f : 0.0f;
  for (int p = tid; p < NP; p += 256) {
    float al = s_al[p] * inv;
    s_al[p] = al;
    out_alph[((size_t)b * NT + t) * NP + p] = al * mk;
  }
  // embedding slot of xh
  int tok = captions[(size_t)order[b] * NL + t];
  for (int e = tid; e < NE; e += 256)
    xh[(size_t)b * KXH + e] = f2b(emb[(size_t)tok * NE + e]);
  __syncthreads();
  // attw (8 e's per thread) + beta gate
  int e0 = tid * 8;
  float acc8[8] = {};
  const u16* fb = featsb + (size_t)b * NP * NENC + e0;
  for (int p = 0; p < NP; ++p) {
    u16x8 v = *(const u16x8*)(fb + (size_t)p * NENC);
    float al = s_al[p];
#pragma unroll
    for (int j = 0; j < 8; ++j) acc8[j] += al * b2f(v[j]);
  }
#pragma unroll
  for (int j = 0; j < 8; ++j) {
    int e = e0 + j;
    float g = sigmoidf_(gate_raw[(size_t)b * NENC + e]);
    xh[(size_t)b * KXH + NE + e] = f2b(acc8[j] * g);
  }
}

// ---------------- gates GEMM + LSTM epilogue ----------------
__global__ __launch_bounds__(256) void kGatesLstm(const u16* __restrict__ xh,  // [128][3072]
                                                  const u16* __restrict__ BT,  // [2048][3072] interleaved
                                                  const float* __restrict__ b_ih,
                                                  const float* __restrict__ b_hh,
                                                  const int* __restrict__ dlen, int t,
                                                  float* __restrict__ c,
                                                  u16* __restrict__ hb,
                                                  u16* __restrict__ hnewb,
                                                  u16* __restrict__ xh_out) {
  __shared__ float ts[128][68];
  int w = threadIdx.x >> 6, lane = threadIdx.x & 63;
  int lr = lane & 15, lg = lane >> 4;
  int mb = w * 32;
  int nb = blockIdx.x * 64;
  f32x4 acc[2][4] = {};
  const u16* a0 = xh + (size_t)(mb + lr) * KXH + lg * 8;
  const u16* a1 = a0 + 16 * KXH;
  const u16* b0 = BT + (size_t)(nb + lr) * KXH + lg * 8;
  for (int k0 = 0; k0 < KXH; k0 += 32) {
    bf16x8 af0 = *(const bf16x8*)(a0 + k0);
    bf16x8 af1 = *(const bf16x8*)(a1 + k0);
#pragma unroll
    for (int nt = 0; nt < 4; ++nt) {
      bf16x8 bf = *(const bf16x8*)(b0 + (size_t)nt * 16 * KXH + k0);
      acc[0][nt] = MFMA16(af0, bf, acc[0][nt], 0, 0, 0);
      acc[1][nt] = MFMA16(af1, bf, acc[1][nt], 0, 0, 0);
    }
  }
#pragma unroll
  for (int mt = 0; mt < 2; ++mt)
#pragma unroll
    for (int nt = 0; nt < 4; ++nt)
#pragma unroll
      for (int j = 0; j < 4; ++j)
        ts[mb + mt * 16 + lg * 4 + j][nt * 16 + lr] = acc[mt][nt][j];
  __syncthreads();
  int d0 = blockIdx.x * 16;
#pragma unroll
  for (int it = 0; it < 8; ++it) {
    int id = it * 256 + threadIdx.x;  // 0..2047
    int row = id >> 4, dl = id & 15;
    int dg = d0 + dl;
    float gi = ts[row][dl * 4 + 0] + b_ih[dg] + b_hh[dg];
    float gf = ts[row][dl * 4 + 1] + b_ih[ND + dg] + b_hh[ND + dg];
    float gg = ts[row][dl * 4 + 2] + b_ih[2 * ND + dg] + b_hh[2 * ND + dg];
    float go = ts[row][dl * 4 + 3] + b_ih[3 * ND + dg] + b_hh[3 * ND + dg];
    float cold = c[(size_t)row * ND + dg];
    float cn = sigmoidf_(gf) * cold + sigmoidf_(gi) * tanhf(gg);
    float hn = sigmoidf_(go) * tanhf(cn);
    u16 hv = f2b(hn);
    hnewb[(size_t)row * ND + dg] = hv;
    if (dlen[row] > t) {
      c[(size_t)row * ND + dg] = cn;
      hb[(size_t)row * ND + dg] = hv;
      xh_out[(size_t)row * KXH + NE + NENC + dg] = hv;
    }
  }
}

// ---------------- preds = hnew @ W_fc + b_fc (MFMA, masked write) ----------------
__global__ __launch_bounds__(256) void kPreds(const u16* __restrict__ hnewb,  // [128][512]
                                              const u16* __restrict__ BT,     // [NVPAD][512]
                                              const float* __restrict__ b_fc,
                                              const int* __restrict__ dlen, int t,
                                              float* __restrict__ out_pred) {
  int w = threadIdx.x >> 6, lane = threadIdx.x & 63;
  int lr = lane & 15, lg = lane >> 4;
  int mb = w * 32;
  int nb = blockIdx.x * 64;
  f32x4 acc[2][4] = {};
  const u16* a0 = hnewb + (size_t)(mb + lr) * ND + lg * 8;
  const u16* a1 = a0 + 16 * ND;
  const u16* b0 = BT + (size_t)(nb + lr) * ND + lg * 8;
  for (int k0 = 0; k0 < ND; k0 += 32) {
    bf16x8 af0 = *(const bf16x8*)(a0 + k0);
    bf16x8 af1 = *(const bf16x8*)(a1 + k0);
#pragma unroll
    for (int nt = 0; nt < 4; ++nt) {
      bf16x8 bf = *(const bf16x8*)(b0 + (size_t)nt * 16 * ND + k0);
      acc[0][nt] = MFMA16(af0, bf, acc[0][nt], 0, 0, 0);
      acc[1][nt] = MFMA16(af1, bf, acc[1][nt], 0, 0, 0);
    }
  }
#pragma unroll
  for (int mt = 0; mt < 2; ++mt)
#pragma unroll
    for (int nt = 0; nt < 4; ++nt)
#pragma unroll
      for (int j = 0; j < 4; ++j) {
        int gn = nb + nt * 16 + lr;
        if (gn < NV) {
          int row = mb + mt * 16 + lg * 4 + j;
          float mk = (dlen[row] > t) ? 1.0f : 0.0f;
          out_pred[((size_t)row * NT + t) * NV + gn] = mk * (acc[mt][nt][j] + b_fc[gn]);
        }
      }
}

extern "C" void kernel_launch(void* const* d_in, const int* in_sizes, int n_in,
                              void* d_out, int out_size, void* d_ws, size_t ws_size,
                              hipStream_t stream) {
  (void)in_sizes; (void)n_in; (void)out_size; (void)ws_size;
  const float* features  = (const float*)d_in[0];
  const int*   captions  = (const int*)d_in[1];
  const int*   cap_len   = (const int*)d_in[2];
  const float* emb       = (const float*)d_in[3];
  const float* W_enc_att = (const float*)d_in[4];
  const float* b_enc_att = (const float*)d_in[5];
  const float* W_dec_att = (const float*)d_in[6];
  const float* b_dec_att = (const float*)d_in[7];
  const float* w_full    = (const float*)d_in[8];
  const float* b_full    = (const float*)d_in[9];
  const float* W_h0      = (const float*)d_in[10];
  const float* b_h0      = (const float*)d_in[11];
  const float* W_c0      = (const float*)d_in[12];
  const float* b_c0      = (const float*)d_in[13];
  const float* W_beta    = (const float*)d_in[14];
  const float* b_beta    = (const float*)d_in[15];
  const float* W_ih      = (const float*)d_in[16];
  const float* b_ih      = (const float*)d_in[17];
  const float* W_hh      = (const float*)d_in[18];
  const float* b_hh      = (const float*)d_in[19];
  const float* W_fc      = (const float*)d_in[20];
  const float* b_fc      = (const float*)d_in[21];

  float* out      = (float*)d_out;
  float* out_pred = out;
  float* out_cap  = out_pred + (size_t)NB * NT * NV;
  float* out_dlen = out_cap + (size_t)NB * NL;
  float* out_alph = out_dlen + NB;

  char* p = (char*)d_ws;
  auto alloc = [&](size_t nbytes) { void* r = (void*)p; p += (nbytes + 255) & ~(size_t)255; return r; };
  int*   order    = (int*)alloc(NB * 4);
  int*   dlen     = (int*)alloc(NB * 4);
  float* eo       = (float*)alloc((size_t)NB * NENC * 4);
  float* c        = (float*)alloc((size_t)NB * ND * 4);
  u16*   hb       = (u16*)alloc((size_t)NB * ND * 2);
  u16*   hnewb    = (u16*)alloc((size_t)NB * ND * 2);
  u16*   xh       = (u16*)alloc((size_t)NB * KXH * 2);
  float* dec_proj = (float*)alloc((size_t)NB * NA * 4);
  float* gate_raw = (float*)alloc((size_t)NB * NENC * 4);
  u16*   featsb   = (u16*)alloc((size_t)NB * NP * NENC * 2);
  u16*   encb     = (u16*)alloc((size_t)NB * NP * NA * 2);
  u16*   WencT    = (u16*)alloc((size_t)NA * NENC * 2);
  u16*   WdgT     = (u16*)alloc((size_t)(NA + NENC) * ND * 2);
  u16*   WifgoT   = (u16*)alloc((size_t)(4 * ND) * KXH * 2);
  u16*   WfcT     = (u16*)alloc((size_t)NVPAD * ND * 2);

  kSort<<<1, NB, 0, stream>>>(cap_len, captions, order, dlen, out_cap, out_dlen);
  kFeats<<<dim3(NP, NB), 256, 0, stream>>>(features, order, featsb);
  kTWenc<<<NA, 256, 0, stream>>>(W_enc_att, WencT);
  kTdg<<<NA + NENC, 256, 0, stream>>>(W_dec_att, W_beta, WdgT);
  kTifgo<<<4 * ND, 256, 0, stream>>>(W_ih, W_hh, WifgoT);
  kTfc<<<NVPAD, 256, 0, stream>>>(W_fc, WfcT);
  kEo<<<dim3(NENC / 256, NB), 256, 0, stream>>>(featsb, eo);
  kInitHC<<<dim3(ND / 256, NB, 2), 256, 0, stream>>>(eo, W_h0, b_h0, W_c0, b_c0, hb, xh, c);
  kEncProj<<<dim3(NA / 64, (NB * NP) / 128), 256, 0, stream>>>(featsb, WencT, b_enc_att, encb);

  for (int t = 0; t < NT; ++t) {
    kDecGate<<<(NA + NENC) / 64, 256, 0, stream>>>(hb, WdgT, b_dec_att, b_beta, dec_proj, gate_raw);
    kSAX<<<NB, 256, 0, stream>>>(featsb, encb, dec_proj, gate_raw, w_full, b_full,
                                 emb, captions, order, dlen, t, xh, out_alph);
    kGatesLstm<<<(4 * ND) / 64, 256, 0, stream>>>(xh, WifgoT, b_ih, b_hh, dlen, t,
                                                  c, hb, hnewb, xh);
    kPreds<<<NVPAD / 64, 256, 0, stream>>>(hnewb, WfcT, b_fc, dlen, t, out_pred);
  }
}

// Round 3
// 5809.656 us; speedup vs baseline: 2.5678x; 1.4735x over previous
//
#include <hip/hip_runtime.h>
#include <math.h>

#define NB 128
#define NP 196
#define NENC 2048
#define NE 512
#define ND 512
#define NA 512
#define NV 10000
#define NVPAD 10112
#define NL 52
#define NT 51
#define KXH 3072   // [emb 512 | attw 2048 | h 512]

typedef unsigned short u16;
typedef __attribute__((ext_vector_type(8))) short bf16x8;
typedef __attribute__((ext_vector_type(8))) unsigned short u16x8;
typedef __attribute__((ext_vector_type(4))) unsigned short u16x4;
typedef __attribute__((ext_vector_type(4))) float f32x4;

#define MFMA16 __builtin_amdgcn_mfma_f32_16x16x32_bf16

__device__ __forceinline__ float sigmoidf_(float v) { return 1.0f / (1.0f + __expf(-v)); }
__device__ __forceinline__ float b2f(u16 u) { return __uint_as_float(((unsigned int)u) << 16); }
__device__ __forceinline__ u16 f2b(float f) {
  unsigned int u = __float_as_uint(f);
  unsigned int r = (u + 0x7FFFu + ((u >> 16) & 1u)) >> 16;
  return (u16)r;
}

// ---------------- sort (stable, descending) + nact[t] ----------------
__global__ void kSort(const int* __restrict__ cap_len, const int* __restrict__ captions,
                      int* __restrict__ order, int* __restrict__ nact,
                      float* __restrict__ out_cap, float* __restrict__ out_dlen) {
  __shared__ int lens[NB];
  __shared__ int s_dl[NB];
  int tid = threadIdx.x;
  lens[tid] = cap_len[tid];
  __syncthreads();
  int li = lens[tid];
  int r = 0;
  for (int j = 0; j < NB; ++j) {
    int lj = lens[j];
    if (lj > li || (lj == li && j < tid)) r++;
  }
  order[r] = tid;
  s_dl[r] = li - 1;
  out_dlen[r] = (float)(li - 1);
  for (int l = 0; l < NL; ++l)
    out_cap[(size_t)r * NL + l] = (float)captions[(size_t)tid * NL + l];
  __syncthreads();
  if (tid < NT) {
    int cnt = 0;
    for (int j = 0; j < NB; ++j) cnt += (s_dl[j] > tid) ? 1 : 0;
    nact[tid] = cnt;
  }
}

// ---------------- features: gather sorted + f32 -> bf16 ----------------
__global__ void kFeats(const float* __restrict__ features, const int* __restrict__ order,
                       u16* __restrict__ featsb) {
  int p = blockIdx.x, b = blockIdx.y, tid = threadIdx.x;
  const float* src = features + ((size_t)order[b] * NP + p) * NENC + tid * 8;
  u16* dst = featsb + ((size_t)b * NP + p) * NENC + tid * 8;
  float4 v0 = *(const float4*)src;
  float4 v1 = *(const float4*)(src + 4);
  u16x8 o;
  o[0] = f2b(v0.x); o[1] = f2b(v0.y); o[2] = f2b(v0.z); o[3] = f2b(v0.w);
  o[4] = f2b(v1.x); o[5] = f2b(v1.y); o[6] = f2b(v1.z); o[7] = f2b(v1.w);
  *(u16x8*)dst = o;
}

// ---------------- weight transposes (one-time) ----------------
__global__ void kTWenc(const float* __restrict__ W, u16* __restrict__ dst) {
  int n = blockIdx.x;
  for (int k = threadIdx.x; k < NENC; k += 256)
    dst[(size_t)n * NENC + k] = f2b(W[(size_t)k * NA + n]);
}
__global__ void kTdg(const float* __restrict__ Wdec, const float* __restrict__ Wbeta,
                     u16* __restrict__ dst) {
  int n = blockIdx.x;  // 2560
  for (int k = threadIdx.x; k < ND; k += 256) {
    float v = (n < NA) ? Wdec[(size_t)k * NA + n] : Wbeta[(size_t)k * NENC + (n - NA)];
    dst[(size_t)n * ND + k] = f2b(v);
  }
}
__global__ void kTifgo(const float* __restrict__ Wih, const float* __restrict__ Whh,
                       u16* __restrict__ dst) {
  int n = blockIdx.x;  // 2048 (d = n>>2, gate = n&3)
  int col = (n & 3) * ND + (n >> 2);
  for (int k = threadIdx.x; k < KXH; k += 256) {
    float v = (k < NE + NENC) ? Wih[(size_t)k * (4 * ND) + col]
                              : Whh[(size_t)(k - NE - NENC) * (4 * ND) + col];
    dst[(size_t)n * KXH + k] = f2b(v);
  }
}
__global__ void kTfc(const float* __restrict__ Wfc, u16* __restrict__ dst) {
  int n = blockIdx.x;  // NVPAD
  for (int k = threadIdx.x; k < ND; k += 256) {
    float v = (n < NV) ? Wfc[(size_t)k * NV + n] : 0.0f;
    dst[(size_t)n * ND + k] = f2b(v);
  }
}

// ---------------- eo = mean over P ----------------
__global__ void kEo(const u16* __restrict__ featsb, float* __restrict__ eo) {
  int e = blockIdx.x * 256 + threadIdx.x;
  int b = blockIdx.y;
  const u16* f = featsb + (size_t)b * NP * NENC + e;
  float s = 0.0f;
  for (int p = 0; p < NP; ++p) s += b2f(f[(size_t)p * NENC]);
  eo[(size_t)b * NENC + e] = s * (1.0f / NP);
}

// ---------------- h0 / c0 ----------------
__global__ void kInitHC(const float* __restrict__ eo,
                        const float* __restrict__ W_h0, const float* __restrict__ b_h0,
                        const float* __restrict__ W_c0, const float* __restrict__ b_c0,
                        u16* __restrict__ hb, u16* __restrict__ xh0, float* __restrict__ c) {
  __shared__ float s_eo[NENC];
  int b = blockIdx.y;
  for (int i = threadIdx.x; i < NENC; i += 256) s_eo[i] = eo[(size_t)b * NENC + i];
  __syncthreads();
  int d = blockIdx.x * 256 + threadIdx.x;
  const float* W = blockIdx.z ? W_c0 : W_h0;
  const float* bias = blockIdx.z ? b_c0 : b_h0;
  float acc = bias[d];
  for (int k = 0; k < NENC; ++k) acc += s_eo[k] * W[(size_t)k * ND + d];
  if (blockIdx.z) {
    c[(size_t)b * ND + d] = acc;
  } else {
    u16 hv = f2b(acc);
    hb[(size_t)b * ND + d] = hv;
    xh0[(size_t)b * KXH + NE + NENC + d] = hv;
  }
}

// ---------------- enc_proj (MFMA, bf16 out), XCD-locality remap ----------------
__global__ __launch_bounds__(256) void kEncProj(const u16* __restrict__ A,   // [25088][2048]
                                                const u16* __restrict__ BT,  // [512][2048]
                                                const float* __restrict__ bias,
                                                u16* __restrict__ D) {       // [25088][512]
  // grid 1600: c = bid&7 (xcd-class), k = bid>>3 in [0,200): mt = c*25 + k/8, ntile = k&7
  int bid = blockIdx.x;
  int cc = bid & 7;
  int k = bid >> 3;
  int mt = cc * 25 + (k >> 3);
  if (mt >= 196) return;
  int ntile = k & 7;
  int w = threadIdx.x >> 6, lane = threadIdx.x & 63;
  int lr = lane & 15, lg = lane >> 4;
  int mb = mt * 128 + w * 32;
  int nb = ntile * 64;
  f32x4 acc[2][4] = {};
  const u16* a0 = A + (size_t)(mb + lr) * NENC + lg * 8;
  const u16* a1 = a0 + 16 * NENC;
  const u16* b0 = BT + (size_t)(nb + lr) * NENC + lg * 8;
  for (int k0 = 0; k0 < NENC; k0 += 32) {
    bf16x8 af0 = *(const bf16x8*)(a0 + k0);
    bf16x8 af1 = *(const bf16x8*)(a1 + k0);
#pragma unroll
    for (int nt = 0; nt < 4; ++nt) {
      bf16x8 bf = *(const bf16x8*)(b0 + (size_t)nt * 16 * NENC + k0);
      acc[0][nt] = MFMA16(af0, bf, acc[0][nt], 0, 0, 0);
      acc[1][nt] = MFMA16(af1, bf, acc[1][nt], 0, 0, 0);
    }
  }
#pragma unroll
  for (int mt2 = 0; mt2 < 2; ++mt2)
#pragma unroll
    for (int nt = 0; nt < 4; ++nt)
#pragma unroll
      for (int j = 0; j < 4; ++j) {
        int row = mb + mt2 * 16 + lg * 4 + j;
        int col = nb + nt * 16 + lr;
        D[(size_t)row * NA + col] = f2b(acc[mt2][nt][j] + bias[col]);
      }
}

// ---------------- dec_proj & gate_raw (MFMA, nact-aware) ----------------
__global__ __launch_bounds__(256) void kDecGate(const u16* __restrict__ hb,
                                                const u16* __restrict__ BT,   // [2560][512]
                                                const float* __restrict__ b_dec,
                                                const float* __restrict__ b_beta,
                                                const int* __restrict__ nact, int t,
                                                float* __restrict__ dec_proj,
                                                float* __restrict__ gate_raw) {
  int nact_t = nact[t];
  int w = threadIdx.x >> 6, lane = threadIdx.x & 63;
  int lr = lane & 15, lg = lane >> 4;
  int mb = w * 32;
  if (mb >= nact_t) return;
  int nb = blockIdx.x * 64;
  f32x4 acc[2][4] = {};
  const u16* a0 = hb + (size_t)(mb + lr) * ND + lg * 8;
  const u16* a1 = a0 + 16 * ND;
  const u16* b0 = BT + (size_t)(nb + lr) * ND + lg * 8;
  for (int k0 = 0; k0 < ND; k0 += 32) {
    bf16x8 af0 = *(const bf16x8*)(a0 + k0);
    bf16x8 af1 = *(const bf16x8*)(a1 + k0);
#pragma unroll
    for (int nt = 0; nt < 4; ++nt) {
      bf16x8 bf = *(const bf16x8*)(b0 + (size_t)nt * 16 * ND + k0);
      acc[0][nt] = MFMA16(af0, bf, acc[0][nt], 0, 0, 0);
      acc[1][nt] = MFMA16(af1, bf, acc[1][nt], 0, 0, 0);
    }
  }
#pragma unroll
  for (int mt = 0; mt < 2; ++mt)
#pragma unroll
    for (int nt = 0; nt < 4; ++nt)
#pragma unroll
      for (int j = 0; j < 4; ++j) {
        int row = mb + mt * 16 + lg * 4 + j;
        int n = nb + nt * 16 + lr;
        if (n < NA)
          dec_proj[(size_t)row * NA + n] = acc[mt][nt][j] + b_dec[n];
        else
          gate_raw[(size_t)row * NENC + (n - NA)] = acc[mt][nt][j] + b_beta[n - NA];
      }
}

// ---------------- scores + softmax + attw + x build (512 thr, nact-aware) ----------------
__global__ __launch_bounds__(512) void kSAX(const u16* __restrict__ featsb,
                                            const u16* __restrict__ enc_projb,
                                            const float* __restrict__ dec_proj,
                                            const float* __restrict__ gate_raw,
                                            const float* __restrict__ w_full,
                                            const float* __restrict__ b_full,
                                            const float* __restrict__ emb,
                                            const int* __restrict__ captions,
                                            const int* __restrict__ order,
                                            const int* __restrict__ nact, int t,
                                            u16* __restrict__ xh,
                                            float* __restrict__ out_alph) {
  int b = blockIdx.x, tid = threadIdx.x;
  int nact_t = nact[b >= 0 ? t : t];
  nact_t = nact[t];
  if (b >= nact_t) {
    for (int p = tid; p < NP; p += 512) out_alph[((size_t)b * NT + t) * NP + p] = 0.0f;
    return;
  }
  __shared__ float s_dp[NA], s_wf[NA], s_sc[NP], s_al[NP], red[16];
  for (int i = tid; i < NA; i += 512) { s_dp[i] = dec_proj[(size_t)b * NA + i]; s_wf[i] = w_full[i]; }
  __syncthreads();
  int wave = tid >> 6, lane = tid & 63;
  float bf_ = b_full[0];
  for (int p = wave; p < NP; p += 8) {
    const u16* ep = enc_projb + ((size_t)b * NP + p) * NA + lane * 8;
    u16x8 v = *(const u16x8*)ep;
    float acc = 0.0f;
#pragma unroll
    for (int j = 0; j < 8; ++j) {
      int a = lane * 8 + j;
      float vv = b2f(v[j]) + s_dp[a];
      acc += fmaxf(vv, 0.0f) * s_wf[a];
    }
#pragma unroll
    for (int off = 32; off; off >>= 1) acc += __shfl_down(acc, off);
    if (lane == 0) s_sc[p] = acc + bf_;
  }
  __syncthreads();
  float mx = -3.4e38f;
  for (int p = tid; p < NP; p += 512) mx = fmaxf(mx, s_sc[p]);
#pragma unroll
  for (int off = 32; off; off >>= 1) mx = fmaxf(mx, __shfl_down(mx, off));
  if (lane == 0) red[wave] = mx;
  __syncthreads();
  if (tid == 0) {
    float m = red[0];
    for (int i = 1; i < 8; ++i) m = fmaxf(m, red[i]);
    red[0] = m;
  }
  __syncthreads();
  float m2 = red[0];
  float sm = 0.0f;
  for (int p = tid; p < NP; p += 512) { float e = __expf(s_sc[p] - m2); s_al[p] = e; sm += e; }
#pragma unroll
  for (int off = 32; off; off >>= 1) sm += __shfl_down(sm, off);
  if (lane == 0) red[8 + wave] = sm;
  __syncthreads();
  if (tid == 0) {
    float s = 0.0f;
    for (int i = 0; i < 8; ++i) s += red[8 + i];
    red[8] = 1.0f / s;
  }
  __syncthreads();
  float inv = red[8];
  for (int p = tid; p < NP; p += 512) {
    float al = s_al[p] * inv;
    s_al[p] = al;
    out_alph[((size_t)b * NT + t) * NP + p] = al;  // active => mask 1
  }
  // embedding slot
  int tok = captions[(size_t)order[b] * NL + t];
  xh[(size_t)b * KXH + tid] = f2b(emb[(size_t)tok * NE + tid]);
  __syncthreads();
  // attw (4 e's per thread) + beta gate
  int e0 = tid * 4;
  float a0 = 0.f, a1 = 0.f, a2 = 0.f, a3 = 0.f;
  const u16* fb = featsb + (size_t)b * NP * NENC + e0;
#pragma unroll 4
  for (int p = 0; p < NP; ++p) {
    u16x4 v = *(const u16x4*)(fb + (size_t)p * NENC);
    float al = s_al[p];
    a0 += al * b2f(v[0]); a1 += al * b2f(v[1]); a2 += al * b2f(v[2]); a3 += al * b2f(v[3]);
  }
  float g0 = sigmoidf_(gate_raw[(size_t)b * NENC + e0 + 0]);
  float g1 = sigmoidf_(gate_raw[(size_t)b * NENC + e0 + 1]);
  float g2 = sigmoidf_(gate_raw[(size_t)b * NENC + e0 + 2]);
  float g3 = sigmoidf_(gate_raw[(size_t)b * NENC + e0 + 3]);
  u16x4 o;
  o[0] = f2b(a0 * g0); o[1] = f2b(a1 * g1); o[2] = f2b(a2 * g2); o[3] = f2b(a3 * g3);
  *(u16x4*)(xh + (size_t)b * KXH + NE + e0) = o;
}

// ---------------- gates GEMM + LSTM epilogue (N-tile 32, ping-pong xh) ----------------
__global__ __launch_bounds__(256) void kGatesLstm(const u16* __restrict__ xh_r,   // read [128][3072]
                                                  const u16* __restrict__ BT,     // [2048][3072]
                                                  const float* __restrict__ b_ih,
                                                  const float* __restrict__ b_hh,
                                                  const int* __restrict__ nact, int t,
                                                  float* __restrict__ c,
                                                  u16* __restrict__ hb,
                                                  u16* __restrict__ hnewAll_t,
                                                  u16* __restrict__ xh_w) {       // write h-slot
  __shared__ float ts[128][33];
  int nact_t = nact[t];
  int w = threadIdx.x >> 6, lane = threadIdx.x & 63;
  int lr = lane & 15, lg = lane >> 4;
  int mb = w * 32;
  int nb = blockIdx.x * 32;
  f32x4 acc[2][2] = {};
  if (mb < nact_t) {
    const u16* a0 = xh_r + (size_t)(mb + lr) * KXH + lg * 8;
    const u16* a1 = a0 + 16 * KXH;
    const u16* b0 = BT + (size_t)(nb + lr) * KXH + lg * 8;
    const u16* b1 = b0 + (size_t)16 * KXH;
    for (int k0 = 0; k0 < KXH; k0 += 32) {
      bf16x8 af0 = *(const bf16x8*)(a0 + k0);
      bf16x8 af1 = *(const bf16x8*)(a1 + k0);
      bf16x8 bv0 = *(const bf16x8*)(b0 + k0);
      bf16x8 bv1 = *(const bf16x8*)(b1 + k0);
      acc[0][0] = MFMA16(af0, bv0, acc[0][0], 0, 0, 0);
      acc[1][0] = MFMA16(af1, bv0, acc[1][0], 0, 0, 0);
      acc[0][1] = MFMA16(af0, bv1, acc[0][1], 0, 0, 0);
      acc[1][1] = MFMA16(af1, bv1, acc[1][1], 0, 0, 0);
    }
  }
#pragma unroll
  for (int mt = 0; mt < 2; ++mt)
#pragma unroll
    for (int nt = 0; nt < 2; ++nt)
#pragma unroll
      for (int j = 0; j < 4; ++j)
        ts[mb + mt * 16 + lg * 4 + j][nt * 16 + lr] = acc[mt][nt][j];
  __syncthreads();
  int d0 = blockIdx.x * 8;
#pragma unroll
  for (int it = 0; it < 4; ++it) {
    int id = it * 256 + threadIdx.x;  // 0..1023
    int row = id >> 3, dl = id & 7;
    int dg = d0 + dl;
    size_t off = (size_t)row * ND + dg;
    if (row < nact_t) {
      float gi = ts[row][dl * 4 + 0] + b_ih[dg] + b_hh[dg];
      float gf = ts[row][dl * 4 + 1] + b_ih[ND + dg] + b_hh[ND + dg];
      float gg = ts[row][dl * 4 + 2] + b_ih[2 * ND + dg] + b_hh[2 * ND + dg];
      float go = ts[row][dl * 4 + 3] + b_ih[3 * ND + dg] + b_hh[3 * ND + dg];
      float cn = sigmoidf_(gf) * c[off] + sigmoidf_(gi) * tanhf(gg);
      float hn = sigmoidf_(go) * tanhf(cn);
      u16 hv = f2b(hn);
      hnewAll_t[off] = hv;
      c[off] = cn;
      hb[off] = hv;
      xh_w[(size_t)row * KXH + NE + NENC + dg] = hv;
    } else {
      hnewAll_t[off] = 0;
      xh_w[(size_t)row * KXH + NE + NENC + dg] = hb[off];  // carry frozen h
    }
  }
}

// ---------------- batched preds GEMM (post-loop) ----------------
__global__ __launch_bounds__(256) void kPredsAll(const u16* __restrict__ hnewAll, // [NT][128][512]
                                                 const u16* __restrict__ BT,      // [NVPAD][512]
                                                 const float* __restrict__ b_fc,
                                                 const int* __restrict__ nact,
                                                 float* __restrict__ out_pred) {
  int t = blockIdx.y;
  int nact_t = nact[t];
  int w = threadIdx.x >> 6, lane = threadIdx.x & 63;
  int lr = lane & 15, lg = lane >> 4;
  int mb = w * 32;
  int nb = blockIdx.x * 64;
  f32x4 acc[2][4] = {};
  if (mb < nact_t) {
    const u16* a0 = hnewAll + (size_t)t * NB * ND + (size_t)(mb + lr) * ND + lg * 8;
    const u16* a1 = a0 + 16 * ND;
    const u16* b0 = BT + (size_t)(nb + lr) * ND + lg * 8;
    for (int k0 = 0; k0 < ND; k0 += 32) {
      bf16x8 af0 = *(const bf16x8*)(a0 + k0);
      bf16x8 af1 = *(const bf16x8*)(a1 + k0);
#pragma unroll
      for (int nt = 0; nt < 4; ++nt) {
        bf16x8 bf = *(const bf16x8*)(b0 + (size_t)nt * 16 * ND + k0);
        acc[0][nt] = MFMA16(af0, bf, acc[0][nt], 0, 0, 0);
        acc[1][nt] = MFMA16(af1, bf, acc[1][nt], 0, 0, 0);
      }
    }
  }
#pragma unroll
  for (int mt = 0; mt < 2; ++mt)
#pragma unroll
    for (int nt = 0; nt < 4; ++nt)
#pragma unroll
      for (int j = 0; j < 4; ++j) {
        int gn = nb + nt * 16 + lr;
        if (gn < NV) {
          int row = mb + mt * 16 + lg * 4 + j;
          float v = (row < nact_t) ? (acc[mt][nt][j] + b_fc[gn]) : 0.0f;
          __builtin_nontemporal_store(v, &out_pred[((size_t)row * NT + t) * NV + gn]);
        }
      }
}

extern "C" void kernel_launch(void* const* d_in, const int* in_sizes, int n_in,
                              void* d_out, int out_size, void* d_ws, size_t ws_size,
                              hipStream_t stream) {
  (void)in_sizes; (void)n_in; (void)out_size; (void)ws_size;
  const float* features  = (const float*)d_in[0];
  const int*   captions  = (const int*)d_in[1];
  const int*   cap_len   = (const int*)d_in[2];
  const float* emb       = (const float*)d_in[3];
  const float* W_enc_att = (const float*)d_in[4];
  const float* b_enc_att = (const float*)d_in[5];
  const float* W_dec_att = (const float*)d_in[6];
  const float* b_dec_att = (const float*)d_in[7];
  const float* w_full    = (const float*)d_in[8];
  const float* b_full    = (const float*)d_in[9];
  const float* W_h0      = (const float*)d_in[10];
  const float* b_h0      = (const float*)d_in[11];
  const float* W_c0      = (const float*)d_in[12];
  const float* b_c0      = (const float*)d_in[13];
  const float* W_beta    = (const float*)d_in[14];
  const float* b_beta    = (const float*)d_in[15];
  const float* W_ih      = (const float*)d_in[16];
  const float* b_ih      = (const float*)d_in[17];
  const float* W_hh      = (const float*)d_in[18];
  const float* b_hh      = (const float*)d_in[19];
  const float* W_fc      = (const float*)d_in[20];
  const float* b_fc      = (const float*)d_in[21];

  float* out      = (float*)d_out;
  float* out_pred = out;
  float* out_cap  = out_pred + (size_t)NB * NT * NV;
  float* out_dlen = out_cap + (size_t)NB * NL;
  float* out_alph = out_dlen + NB;

  char* p = (char*)d_ws;
  auto alloc = [&](size_t nbytes) { void* r = (void*)p; p += (nbytes + 255) & ~(size_t)255; return r; };
  int*   order    = (int*)alloc(NB * 4);
  int*   nact     = (int*)alloc(NT * 4);
  float* eo       = (float*)alloc((size_t)NB * NENC * 4);
  float* c        = (float*)alloc((size_t)NB * ND * 4);
  u16*   hb       = (u16*)alloc((size_t)NB * ND * 2);
  u16*   xh0      = (u16*)alloc((size_t)NB * KXH * 2);
  u16*   xh1      = (u16*)alloc((size_t)NB * KXH * 2);
  u16*   hnewAll  = (u16*)alloc((size_t)NT * NB * ND * 2);
  float* dec_proj = (float*)alloc((size_t)NB * NA * 4);
  float* gate_raw = (float*)alloc((size_t)NB * NENC * 4);
  u16*   featsb   = (u16*)alloc((size_t)NB * NP * NENC * 2);
  u16*   encb     = (u16*)alloc((size_t)NB * NP * NA * 2);
  u16*   WencT    = (u16*)alloc((size_t)NA * NENC * 2);
  u16*   WdgT     = (u16*)alloc((size_t)(NA + NENC) * ND * 2);
  u16*   WifgoT   = (u16*)alloc((size_t)(4 * ND) * KXH * 2);
  u16*   WfcT     = (u16*)alloc((size_t)NVPAD * ND * 2);

  kSort<<<1, NB, 0, stream>>>(cap_len, captions, order, nact, out_cap, out_dlen);
  kFeats<<<dim3(NP, NB), 256, 0, stream>>>(features, order, featsb);
  kTWenc<<<NA, 256, 0, stream>>>(W_enc_att, WencT);
  kTdg<<<NA + NENC, 256, 0, stream>>>(W_dec_att, W_beta, WdgT);
  kTifgo<<<4 * ND, 256, 0, stream>>>(W_ih, W_hh, WifgoT);
  kTfc<<<NVPAD, 256, 0, stream>>>(W_fc, WfcT);
  kEo<<<dim3(NENC / 256, NB), 256, 0, stream>>>(featsb, eo);
  kInitHC<<<dim3(ND / 256, NB, 2), 256, 0, stream>>>(eo, W_h0, b_h0, W_c0, b_c0, hb, xh0, c);
  kEncProj<<<1600, 256, 0, stream>>>(featsb, WencT, b_enc_att, encb);

  for (int t = 0; t < NT; ++t) {
    u16* xh_r = (t & 1) ? xh1 : xh0;
    u16* xh_w = (t & 1) ? xh0 : xh1;
    kDecGate<<<(NA + NENC) / 64, 256, 0, stream>>>(hb, WdgT, b_dec_att, b_beta, nact, t,
                                                   dec_proj, gate_raw);
    kSAX<<<NB, 512, 0, stream>>>(featsb, encb, dec_proj, gate_raw, w_full, b_full,
                                 emb, captions, order, nact, t, xh_r, out_alph);
    kGatesLstm<<<(4 * ND) / 32, 256, 0, stream>>>(xh_r, WifgoT, b_ih, b_hh, nact, t,
                                                  c, hb, hnewAll + (size_t)t * NB * ND, xh_w);
  }
  kPredsAll<<<dim3(NVPAD / 64, NT), 256, 0, stream>>>(hnewAll, WfcT, b_fc, nact, out_pred);
}

// Round 4
// 4983.937 us; speedup vs baseline: 2.9933x; 1.1657x over previous
//
#include <hip/hip_runtime.h>
#include <math.h>

#define NB 128
#define NP 196
#define NENC 2048
#define NE 512
#define ND 512
#define NA 512
#define NV 10000
#define NVPAD 10112
#define NL 52
#define NT 51
#define KXH 3072   // [emb 512 | attw 2048 | h 512]

typedef unsigned short u16;
typedef __attribute__((ext_vector_type(8))) short bf16x8;
typedef __attribute__((ext_vector_type(8))) unsigned short u16x8;
typedef __attribute__((ext_vector_type(4))) float f32x4;

#define MFMA16 __builtin_amdgcn_mfma_f32_16x16x32_bf16

__device__ __forceinline__ float sigmoidf_(float v) { return 1.0f / (1.0f + __expf(-v)); }
__device__ __forceinline__ float b2f(u16 u) { return __uint_as_float(((unsigned int)u) << 16); }
__device__ __forceinline__ u16 f2b(float f) {
  unsigned int u = __float_as_uint(f);
  unsigned int r = (u + 0x7FFFu + ((u >> 16) & 1u)) >> 16;
  return (u16)r;
}

// ---------------- sort (stable, descending) + nact[t] ----------------
__global__ void kSort(const int* __restrict__ cap_len, const int* __restrict__ captions,
                      int* __restrict__ order, int* __restrict__ nact,
                      float* __restrict__ out_cap, float* __restrict__ out_dlen) {
  __shared__ int lens[NB];
  __shared__ int s_dl[NB];
  int tid = threadIdx.x;
  lens[tid] = cap_len[tid];
  __syncthreads();
  int li = lens[tid];
  int r = 0;
  for (int j = 0; j < NB; ++j) {
    int lj = lens[j];
    if (lj > li || (lj == li && j < tid)) r++;
  }
  order[r] = tid;
  s_dl[r] = li - 1;
  out_dlen[r] = (float)(li - 1);
  for (int l = 0; l < NL; ++l)
    out_cap[(size_t)r * NL + l] = (float)captions[(size_t)tid * NL + l];
  __syncthreads();
  if (tid < NT) {
    int cnt = 0;
    for (int j = 0; j < NB; ++j) cnt += (s_dl[j] > tid) ? 1 : 0;
    nact[tid] = cnt;
  }
}

// ---------------- zero alphas for inactive (b,t) upfront ----------------
__global__ void kAlphaZero(const int* __restrict__ nact, float* __restrict__ out_alph) {
  int t = blockIdx.x;
  int n0 = nact[t];
  int cnt = (NB - n0) * NP;
  for (int i = threadIdx.x; i < cnt; i += 256) {
    int b = n0 + i / NP;
    int p = i - (i / NP) * NP;
    out_alph[((size_t)b * NT + t) * NP + p] = 0.0f;
  }
}

// ---------------- features: gather sorted + f32 -> bf16 ----------------
__global__ void kFeats(const float* __restrict__ features, const int* __restrict__ order,
                       u16* __restrict__ featsb) {
  int p = blockIdx.x, b = blockIdx.y, tid = threadIdx.x;
  const float* src = features + ((size_t)order[b] * NP + p) * NENC + tid * 8;
  u16* dst = featsb + ((size_t)b * NP + p) * NENC + tid * 8;
  float4 v0 = *(const float4*)src;
  float4 v1 = *(const float4*)(src + 4);
  u16x8 o;
  o[0] = f2b(v0.x); o[1] = f2b(v0.y); o[2] = f2b(v0.z); o[3] = f2b(v0.w);
  o[4] = f2b(v1.x); o[5] = f2b(v1.y); o[6] = f2b(v1.z); o[7] = f2b(v1.w);
  *(u16x8*)dst = o;
}

// ---------------- weight transposes (one-time) ----------------
__global__ void kTWenc(const float* __restrict__ W, u16* __restrict__ dst) {
  int n = blockIdx.x;
  for (int k = threadIdx.x; k < NENC; k += 256)
    dst[(size_t)n * NENC + k] = f2b(W[(size_t)k * NA + n]);
}
__global__ void kTdg(const float* __restrict__ Wdec, const float* __restrict__ Wbeta,
                     u16* __restrict__ dst) {
  int n = blockIdx.x;  // 2560
  for (int k = threadIdx.x; k < ND; k += 256) {
    float v = (n < NA) ? Wdec[(size_t)k * NA + n] : Wbeta[(size_t)k * NENC + (n - NA)];
    dst[(size_t)n * ND + k] = f2b(v);
  }
}
__global__ void kTifgo(const float* __restrict__ Wih, const float* __restrict__ Whh,
                       u16* __restrict__ dst) {
  int n = blockIdx.x;  // 2048 (d = n>>2, gate = n&3)
  int col = (n & 3) * ND + (n >> 2);
  for (int k = threadIdx.x; k < KXH; k += 256) {
    float v = (k < NE + NENC) ? Wih[(size_t)k * (4 * ND) + col]
                              : Whh[(size_t)(k - NE - NENC) * (4 * ND) + col];
    dst[(size_t)n * KXH + k] = f2b(v);
  }
}
__global__ void kTfc(const float* __restrict__ Wfc, u16* __restrict__ dst) {
  int n = blockIdx.x;  // NVPAD
  for (int k = threadIdx.x; k < ND; k += 256) {
    float v = (n < NV) ? Wfc[(size_t)k * NV + n] : 0.0f;
    dst[(size_t)n * ND + k] = f2b(v);
  }
}

// ---------------- eo = mean over P ----------------
__global__ void kEo(const u16* __restrict__ featsb, float* __restrict__ eo) {
  int e = blockIdx.x * 256 + threadIdx.x;
  int b = blockIdx.y;
  const u16* f = featsb + (size_t)b * NP * NENC + e;
  float s = 0.0f;
  for (int p = 0; p < NP; ++p) s += b2f(f[(size_t)p * NENC]);
  eo[(size_t)b * NENC + e] = s * (1.0f / NP);
}

// ---------------- h0 / c0 ----------------
__global__ void kInitHC(const float* __restrict__ eo,
                        const float* __restrict__ W_h0, const float* __restrict__ b_h0,
                        const float* __restrict__ W_c0, const float* __restrict__ b_c0,
                        u16* __restrict__ hb, u16* __restrict__ xh0, float* __restrict__ c) {
  __shared__ float s_eo[NENC];
  int b = blockIdx.y;
  for (int i = threadIdx.x; i < NENC; i += 256) s_eo[i] = eo[(size_t)b * NENC + i];
  __syncthreads();
  int d = blockIdx.x * 256 + threadIdx.x;
  const float* W = blockIdx.z ? W_c0 : W_h0;
  const float* bias = blockIdx.z ? b_c0 : b_h0;
  float acc = bias[d];
  for (int k = 0; k < NENC; ++k) acc += s_eo[k] * W[(size_t)k * ND + d];
  if (blockIdx.z) {
    c[(size_t)b * ND + d] = acc;
  } else {
    u16 hv = f2b(acc);
    hb[(size_t)b * ND + d] = hv;
    xh0[(size_t)b * KXH + NE + NENC + d] = hv;
  }
}

// ---------------- enc_proj (MFMA, bf16 out), XCD-locality remap ----------------
__global__ __launch_bounds__(256) void kEncProj(const u16* __restrict__ A,
                                                const u16* __restrict__ BT,
                                                const float* __restrict__ bias,
                                                u16* __restrict__ D) {
  int bid = blockIdx.x;
  int cc = bid & 7;
  int k = bid >> 3;
  int mt = cc * 25 + (k >> 3);
  if (mt >= 196) return;
  int ntile = k & 7;
  int w = threadIdx.x >> 6, lane = threadIdx.x & 63;
  int lr = lane & 15, lg = lane >> 4;
  int mb = mt * 128 + w * 32;
  int nb = ntile * 64;
  f32x4 acc[2][4] = {};
  const u16* a0 = A + (size_t)(mb + lr) * NENC + lg * 8;
  const u16* a1 = a0 + 16 * NENC;
  const u16* b0 = BT + (size_t)(nb + lr) * NENC + lg * 8;
  for (int k0 = 0; k0 < NENC; k0 += 32) {
    bf16x8 af0 = *(const bf16x8*)(a0 + k0);
    bf16x8 af1 = *(const bf16x8*)(a1 + k0);
#pragma unroll
    for (int nt = 0; nt < 4; ++nt) {
      bf16x8 bf = *(const bf16x8*)(b0 + (size_t)nt * 16 * NENC + k0);
      acc[0][nt] = MFMA16(af0, bf, acc[0][nt], 0, 0, 0);
      acc[1][nt] = MFMA16(af1, bf, acc[1][nt], 0, 0, 0);
    }
  }
#pragma unroll
  for (int mt2 = 0; mt2 < 2; ++mt2)
#pragma unroll
    for (int nt = 0; nt < 4; ++nt)
#pragma unroll
      for (int j = 0; j < 4; ++j) {
        int row = mb + mt2 * 16 + lg * 4 + j;
        int col = nb + nt * 16 + lr;
        D[(size_t)row * NA + col] = f2b(acc[mt2][nt][j] + bias[col]);
      }
}

// ---------------- dec_proj & gate_raw: 32x32 tiles, 1-wave blocks ----------------
__global__ __launch_bounds__(64) void kDecGate(const u16* __restrict__ hb,
                                               const u16* __restrict__ BT,   // [2560][512]
                                               const float* __restrict__ b_dec,
                                               const float* __restrict__ b_beta,
                                               const int* __restrict__ nact, int t,
                                               float* __restrict__ dec_proj,
                                               float* __restrict__ gate_raw) {
  int nact_t = nact[t];
  int mb = blockIdx.y * 32;
  if (mb >= nact_t) return;
  int lane = threadIdx.x;
  int lr = lane & 15, lg = lane >> 4;
  int nb = blockIdx.x * 32;
  f32x4 acc[2][2] = {};
  const u16* a0 = hb + (size_t)(mb + lr) * ND + lg * 8;
  const u16* a1 = a0 + 16 * ND;
  const u16* b0 = BT + (size_t)(nb + lr) * ND + lg * 8;
  const u16* b1 = b0 + 16 * ND;
#pragma unroll 4
  for (int k0 = 0; k0 < ND; k0 += 32) {
    bf16x8 af0 = *(const bf16x8*)(a0 + k0);
    bf16x8 af1 = *(const bf16x8*)(a1 + k0);
    bf16x8 bv0 = *(const bf16x8*)(b0 + k0);
    bf16x8 bv1 = *(const bf16x8*)(b1 + k0);
    acc[0][0] = MFMA16(af0, bv0, acc[0][0], 0, 0, 0);
    acc[1][0] = MFMA16(af1, bv0, acc[1][0], 0, 0, 0);
    acc[0][1] = MFMA16(af0, bv1, acc[0][1], 0, 0, 0);
    acc[1][1] = MFMA16(af1, bv1, acc[1][1], 0, 0, 0);
  }
#pragma unroll
  for (int mt = 0; mt < 2; ++mt)
#pragma unroll
    for (int nt = 0; nt < 2; ++nt)
#pragma unroll
      for (int j = 0; j < 4; ++j) {
        int row = mb + mt * 16 + lg * 4 + j;
        int n = nb + nt * 16 + lr;
        if (n < NA)
          dec_proj[(size_t)row * NA + n] = acc[mt][nt][j] + b_dec[n];
        else
          gate_raw[(size_t)row * NENC + (n - NA)] = acc[mt][nt][j] + b_beta[n - NA];
      }
}

// ---------------- scores+softmax (redundant x4) + attw 512-col slice + xh ----------------
__global__ __launch_bounds__(256) void kSAX(const u16* __restrict__ featsb,
                                            const u16* __restrict__ enc_projb,
                                            const float* __restrict__ dec_proj,
                                            const float* __restrict__ gate_raw,
                                            const float* __restrict__ w_full,
                                            const float* __restrict__ b_full,
                                            const float* __restrict__ emb,
                                            const int* __restrict__ captions,
                                            const int* __restrict__ order,
                                            const int* __restrict__ nact, int t,
                                            u16* __restrict__ xh,
                                            float* __restrict__ out_alph) {
  int b = blockIdx.x, r = blockIdx.y, tid = threadIdx.x;
  int nact_t = nact[t];
  if (b >= nact_t) return;
  __shared__ float s_dp[NA], s_wf[NA], s_al[NP], red[16];
  for (int i = tid; i < NA; i += 256) { s_dp[i] = dec_proj[(size_t)b * NA + i]; s_wf[i] = w_full[i]; }
  __syncthreads();
  int wave = tid >> 6, lane = tid & 63;
  float bf_ = b_full[0];
  for (int p = wave; p < NP; p += 4) {
    const u16* ep = enc_projb + ((size_t)b * NP + p) * NA + lane * 8;
    u16x8 v = *(const u16x8*)ep;
    float acc = 0.0f;
#pragma unroll
    for (int j = 0; j < 8; ++j) {
      int a = lane * 8 + j;
      float vv = b2f(v[j]) + s_dp[a];
      acc += fmaxf(vv, 0.0f) * s_wf[a];
    }
#pragma unroll
    for (int off = 32; off; off >>= 1) acc += __shfl_down(acc, off);
    if (lane == 0) s_al[p] = acc + bf_;
  }
  __syncthreads();
  float mx = -3.4e38f;
  for (int p = tid; p < NP; p += 256) mx = fmaxf(mx, s_al[p]);
#pragma unroll
  for (int off = 32; off; off >>= 1) mx = fmaxf(mx, __shfl_down(mx, off));
  if (lane == 0) red[wave] = mx;
  __syncthreads();
  if (tid == 0) red[0] = fmaxf(fmaxf(red[0], red[1]), fmaxf(red[2], red[3]));
  __syncthreads();
  float m2 = red[0];
  float sm = 0.0f;
  for (int p = tid; p < NP; p += 256) { float e = __expf(s_al[p] - m2); s_al[p] = e; sm += e; }
#pragma unroll
  for (int off = 32; off; off >>= 1) sm += __shfl_down(sm, off);
  if (lane == 0) red[8 + wave] = sm;
  __syncthreads();
  if (tid == 0) red[8] = 1.0f / (red[8] + red[9] + red[10] + red[11]);
  __syncthreads();
  float inv = red[8];
  for (int p = tid; p < NP; p += 256) {
    float al = s_al[p] * inv;
    s_al[p] = al;
    if (r == 0) out_alph[((size_t)b * NT + t) * NP + p] = al;
  }
  if (r == 0) {
    int tok = captions[(size_t)order[b] * NL + t];
    int e = tid * 2;
    unsigned int w0 = f2b(emb[(size_t)tok * NE + e]) | ((unsigned int)f2b(emb[(size_t)tok * NE + e + 1]) << 16);
    *(unsigned int*)(xh + (size_t)b * KXH + e) = w0;
  }
  __syncthreads();
  // attw for cols [r*512, r*512+512): 2 cols per thread
  int e0 = r * 512 + tid * 2;
  float ac0 = 0.0f, ac1 = 0.0f;
  const u16* fb = featsb + (size_t)b * NP * NENC + e0;
#pragma unroll 4
  for (int p = 0; p < NP; ++p) {
    unsigned int v = *(const unsigned int*)(fb + (size_t)p * NENC);
    float al = s_al[p];
    ac0 += al * __uint_as_float(v << 16);
    ac1 += al * __uint_as_float(v & 0xffff0000u);
  }
  float g0 = sigmoidf_(gate_raw[(size_t)b * NENC + e0]);
  float g1 = sigmoidf_(gate_raw[(size_t)b * NENC + e0 + 1]);
  unsigned int wo = f2b(ac0 * g0) | ((unsigned int)f2b(ac1 * g1) << 16);
  *(unsigned int*)(xh + (size_t)b * KXH + NE + e0) = wo;
}

// ---------------- gates GEMM (4-way K-split) + LSTM epilogue ----------------
__global__ __launch_bounds__(1024) void kGatesLstm(const u16* __restrict__ xh_r,
                                                   const u16* __restrict__ BT,  // [2048][3072]
                                                   const float* __restrict__ b_ih,
                                                   const float* __restrict__ b_hh,
                                                   const int* __restrict__ nact, int t,
                                                   float* __restrict__ c,
                                                   u16* __restrict__ hb,
                                                   u16* __restrict__ hnewAll_t,
                                                   u16* __restrict__ xh_w) {
  __shared__ float s_g[16][32][17];
  int nact_t = nact[t];
  int tid = threadIdx.x;
  int w = tid >> 6, lane = tid & 63;
  int lr = lane & 15, lg = lane >> 4;
  int rt = w & 3, kq = w >> 2;
  int nb = blockIdx.x * 16;
  f32x4 acc0 = {}, acc1 = {};
  if (rt * 32 < nact_t) {
    const u16* a0 = xh_r + (size_t)(rt * 32 + lr) * KXH + kq * 768 + lg * 8;
    const u16* a1 = a0 + 16 * KXH;
    const u16* b0 = BT + (size_t)(nb + lr) * KXH + kq * 768 + lg * 8;
#pragma unroll 4
    for (int k0 = 0; k0 < 768; k0 += 32) {
      bf16x8 af0 = *(const bf16x8*)(a0 + k0);
      bf16x8 af1 = *(const bf16x8*)(a1 + k0);
      bf16x8 bf = *(const bf16x8*)(b0 + k0);
      acc0 = MFMA16(af0, bf, acc0, 0, 0, 0);
      acc1 = MFMA16(af1, bf, acc1, 0, 0, 0);
    }
  }
#pragma unroll
  for (int j = 0; j < 4; ++j) {
    s_g[w][lg * 4 + j][lr] = acc0[j];
    s_g[w][16 + lg * 4 + j][lr] = acc1[j];
  }
  __syncthreads();
  if (tid < 512) {
    int row = tid >> 2, dl = tid & 3;
    int rt2 = row >> 5, r32 = row & 31;
    int d = blockIdx.x * 4 + dl;
    int cl = dl * 4;
    float g4[4];
#pragma unroll
    for (int g = 0; g < 4; ++g)
      g4[g] = s_g[rt2][r32][cl + g] + s_g[4 + rt2][r32][cl + g] +
              s_g[8 + rt2][r32][cl + g] + s_g[12 + rt2][r32][cl + g];
    size_t off = (size_t)row * ND + d;
    if (row < nact_t) {
      float gi = g4[0] + b_ih[d] + b_hh[d];
      float gf = g4[1] + b_ih[ND + d] + b_hh[ND + d];
      float gg = g4[2] + b_ih[2 * ND + d] + b_hh[2 * ND + d];
      float go = g4[3] + b_ih[3 * ND + d] + b_hh[3 * ND + d];
      float cn = sigmoidf_(gf) * c[off] + sigmoidf_(gi) * tanhf(gg);
      float hn = sigmoidf_(go) * tanhf(cn);
      u16 hv = f2b(hn);
      c[off] = cn;
      hb[off] = hv;
      hnewAll_t[off] = hv;
      xh_w[(size_t)row * KXH + NE + NENC + d] = hv;
    } else {
      xh_w[(size_t)row * KXH + NE + NENC + d] = hb[off];
    }
  }
}

// ---------------- batched preds GEMM (post-loop) ----------------
__global__ __launch_bounds__(256) void kPredsAll(const u16* __restrict__ hnewAll,
                                                 const u16* __restrict__ BT,
                                                 const float* __restrict__ b_fc,
                                                 const int* __restrict__ nact,
                                                 float* __restrict__ out_pred) {
  int t = blockIdx.y;
  int nact_t = nact[t];
  int w = threadIdx.x >> 6, lane = threadIdx.x & 63;
  int lr = lane & 15, lg = lane >> 4;
  int mb = w * 32;
  int nb = blockIdx.x * 64;
  f32x4 acc[2][4] = {};
  if (mb < nact_t) {
    const u16* a0 = hnewAll + (size_t)t * NB * ND + (size_t)(mb + lr) * ND + lg * 8;
    const u16* a1 = a0 + 16 * ND;
    const u16* b0 = BT + (size_t)(nb + lr) * ND + lg * 8;
    for (int k0 = 0; k0 < ND; k0 += 32) {
      bf16x8 af0 = *(const bf16x8*)(a0 + k0);
      bf16x8 af1 = *(const bf16x8*)(a1 + k0);
#pragma unroll
      for (int nt = 0; nt < 4; ++nt) {
        bf16x8 bf = *(const bf16x8*)(b0 + (size_t)nt * 16 * ND + k0);
        acc[0][nt] = MFMA16(af0, bf, acc[0][nt], 0, 0, 0);
        acc[1][nt] = MFMA16(af1, bf, acc[1][nt], 0, 0, 0);
      }
    }
  }
#pragma unroll
  for (int mt = 0; mt < 2; ++mt)
#pragma unroll
    for (int nt = 0; nt < 4; ++nt)
#pragma unroll
      for (int j = 0; j < 4; ++j) {
        int gn = nb + nt * 16 + lr;
        if (gn < NV) {
          int row = mb + mt * 16 + lg * 4 + j;
          float v = (row < nact_t) ? (acc[mt][nt][j] + b_fc[gn]) : 0.0f;
          __builtin_nontemporal_store(v, &out_pred[((size_t)row * NT + t) * NV + gn]);
        }
      }
}

extern "C" void kernel_launch(void* const* d_in, const int* in_sizes, int n_in,
                              void* d_out, int out_size, void* d_ws, size_t ws_size,
                              hipStream_t stream) {
  (void)in_sizes; (void)n_in; (void)out_size; (void)ws_size;
  const float* features  = (const float*)d_in[0];
  const int*   captions  = (const int*)d_in[1];
  const int*   cap_len   = (const int*)d_in[2];
  const float* emb       = (const float*)d_in[3];
  const float* W_enc_att = (const float*)d_in[4];
  const float* b_enc_att = (const float*)d_in[5];
  const float* W_dec_att = (const float*)d_in[6];
  const float* b_dec_att = (const float*)d_in[7];
  const float* w_full    = (const float*)d_in[8];
  const float* b_full    = (const float*)d_in[9];
  const float* W_h0      = (const float*)d_in[10];
  const float* b_h0      = (const float*)d_in[11];
  const float* W_c0      = (const float*)d_in[12];
  const float* b_c0      = (const float*)d_in[13];
  const float* W_beta    = (const float*)d_in[14];
  const float* b_beta    = (const float*)d_in[15];
  const float* W_ih      = (const float*)d_in[16];
  const float* b_ih      = (const float*)d_in[17];
  const float* W_hh      = (const float*)d_in[18];
  const float* b_hh      = (const float*)d_in[19];
  const float* W_fc      = (const float*)d_in[20];
  const float* b_fc      = (const float*)d_in[21];

  float* out      = (float*)d_out;
  float* out_pred = out;
  float* out_cap  = out_pred + (size_t)NB * NT * NV;
  float* out_dlen = out_cap + (size_t)NB * NL;
  float* out_alph = out_dlen + NB;

  char* p = (char*)d_ws;
  auto alloc = [&](size_t nbytes) { void* r = (void*)p; p += (nbytes + 255) & ~(size_t)255; return r; };
  int*   order    = (int*)alloc(NB * 4);
  int*   nact     = (int*)alloc(NT * 4);
  float* eo       = (float*)alloc((size_t)NB * NENC * 4);
  float* c        = (float*)alloc((size_t)NB * ND * 4);
  u16*   hb       = (u16*)alloc((size_t)NB * ND * 2);
  u16*   xh0      = (u16*)alloc((size_t)NB * KXH * 2);
  u16*   xh1      = (u16*)alloc((size_t)NB * KXH * 2);
  u16*   hnewAll  = (u16*)alloc((size_t)NT * NB * ND * 2);
  float* dec_proj = (float*)alloc((size_t)NB * NA * 4);
  float* gate_raw = (float*)alloc((size_t)NB * NENC * 4);
  u16*   featsb   = (u16*)alloc((size_t)NB * NP * NENC * 2);
  u16*   encb     = (u16*)alloc((size_t)NB * NP * NA * 2);
  u16*   WencT    = (u16*)alloc((size_t)NA * NENC * 2);
  u16*   WdgT     = (u16*)alloc((size_t)(NA + NENC) * ND * 2);
  u16*   WifgoT   = (u16*)alloc((size_t)(4 * ND) * KXH * 2);
  u16*   WfcT     = (u16*)alloc((size_t)NVPAD * ND * 2);

  kSort<<<1, NB, 0, stream>>>(cap_len, captions, order, nact, out_cap, out_dlen);
  kAlphaZero<<<NT, 256, 0, stream>>>(nact, out_alph);
  kFeats<<<dim3(NP, NB), 256, 0, stream>>>(features, order, featsb);
  kTWenc<<<NA, 256, 0, stream>>>(W_enc_att, WencT);
  kTdg<<<NA + NENC, 256, 0, stream>>>(W_dec_att, W_beta, WdgT);
  kTifgo<<<4 * ND, 256, 0, stream>>>(W_ih, W_hh, WifgoT);
  kTfc<<<NVPAD, 256, 0, stream>>>(W_fc, WfcT);
  kEo<<<dim3(NENC / 256, NB), 256, 0, stream>>>(featsb, eo);
  kInitHC<<<dim3(ND / 256, NB, 2), 256, 0, stream>>>(eo, W_h0, b_h0, W_c0, b_c0, hb, xh0, c);
  kEncProj<<<1600, 256, 0, stream>>>(featsb, WencT, b_enc_att, encb);

  for (int t = 0; t < NT; ++t) {
    u16* xh_r = (t & 1) ? xh1 : xh0;
    u16* xh_w = (t & 1) ? xh0 : xh1;
    kDecGate<<<dim3((NA + NENC) / 32, 4), 64, 0, stream>>>(hb, WdgT, b_dec_att, b_beta, nact, t,
                                                           dec_proj, gate_raw);
    kSAX<<<dim3(NB, 4), 256, 0, stream>>>(featsb, encb, dec_proj, gate_raw, w_full, b_full,
                                          emb, captions, order, nact, t, xh_r, out_alph);
    kGatesLstm<<<NENC / 16, 1024, 0, stream>>>(xh_r, WifgoT, b_ih, b_hh, nact, t,
                                               c, hb, hnewAll + (size_t)t * NB * ND, xh_w);
  }
  kPredsAll<<<dim3(NVPAD / 64, NT), 256, 0, stream>>>(hnewAll, WfcT, b_fc, nact, out_pred);
}